// Round 3
// baseline (390.300 us; speedup 1.0000x reference)
//
#include <hip/hip_runtime.h>

// Problem constants (from reference)
#define B_    256
#define CIN   48
#define CBOT  8
#define H_    4096
#define SCALE_ 0.35355339059327373f   // 1/sqrt(8)

// Work decomposition: each batch's H split into SPLIT chunks; one block per
// (batch, chunk). 2048 blocks per kernel -> load-balanced streaming.
#define SPLIT    8
#define CHUNK    (H_ / SPLIT)          // 512
#define THREADS  128                   // each thread owns 4 h (one float4)

// ---------------- Kernel 1: kqv = w_down @ x, + gram partials ----------------
// Writes kqv chunk to ws (layout [b][o][h], coalesced) and 36 upper-triangle
// gram partial sums per block to ws_gram[blk][36].
template <bool STORE_KQV>
__global__ __launch_bounds__(THREADS) void k_down(
    const float* __restrict__ x,        // [B, 48, 4096]
    const float* __restrict__ w_down,   // [8, 48]
    float* __restrict__ ws_kqv,         // [B, 8, 4096]
    float* __restrict__ ws_gram)        // [B*SPLIT, 36]
{
    const int blk = blockIdx.x;
    const int b = blk / SPLIT;
    const int s = blk % SPLIT;
    const int t = threadIdx.x;

    __shared__ float s_wdT[CIN * CBOT];   // transposed [c][o]
    __shared__ float s_red[2 * 36];       // 2 waves/block

    // NOTE: 384 elements, 128 threads -> strided loop (R2 bug: single guard
    // left s_wdT[128..383] poisoned).
    for (int i = t; i < CIN * CBOT; i += THREADS) {
        const int c = i >> 3, o = i & 7;
        s_wdT[i] = w_down[o * CIN + c];
    }
    __syncthreads();

    const int h0 = s * CHUNK + (t << 2);
    const float* xb = x + (size_t)b * (CIN * H_);

    float kqv[CBOT][4];
    #pragma unroll
    for (int o = 0; o < CBOT; ++o)
        kqv[o][0] = kqv[o][1] = kqv[o][2] = kqv[o][3] = 0.0f;

    #pragma unroll 8
    for (int c = 0; c < CIN; ++c) {
        const float4 xv = *reinterpret_cast<const float4*>(xb + c * H_ + h0);
        #pragma unroll
        for (int o = 0; o < CBOT; ++o) {
            const float w = s_wdT[c * CBOT + o];
            kqv[o][0] += w * xv.x;
            kqv[o][1] += w * xv.y;
            kqv[o][2] += w * xv.z;
            kqv[o][3] += w * xv.w;
        }
    }

    if (STORE_KQV) {
        float* kb = ws_kqv + (size_t)b * (CBOT * H_);
        #pragma unroll
        for (int o = 0; o < CBOT; ++o) {
            float4 v = make_float4(kqv[o][0], kqv[o][1], kqv[o][2], kqv[o][3]);
            *reinterpret_cast<float4*>(kb + o * H_ + h0) = v;
        }
    }

    // gram upper triangle, per-thread then wave shuffle reduce
    float g[36];
    {
        int idx = 0;
        #pragma unroll
        for (int i = 0; i < CBOT; ++i)
            #pragma unroll
            for (int j = i; j < CBOT; ++j, ++idx)
                g[idx] = kqv[i][0] * kqv[j][0] + kqv[i][1] * kqv[j][1]
                       + kqv[i][2] * kqv[j][2] + kqv[i][3] * kqv[j][3];
    }
    #pragma unroll
    for (int k = 0; k < 36; ++k) {
        float v = g[k];
        v += __shfl_down(v, 32, 64);
        v += __shfl_down(v, 16, 64);
        v += __shfl_down(v,  8, 64);
        v += __shfl_down(v,  4, 64);
        v += __shfl_down(v,  2, 64);
        v += __shfl_down(v,  1, 64);
        g[k] = v;
    }
    const int wave = t >> 6, lane = t & 63;
    if (lane == 0) {
        #pragma unroll
        for (int k = 0; k < 36; ++k) s_red[wave * 36 + k] = g[k];
    }
    __syncthreads();
    if (t < 36) ws_gram[(size_t)blk * 36 + t] = s_red[t] + s_red[36 + t];
}

// ---------------- Kernel 2: softmax(gram) -> z -> out ----------------
template <bool LOAD_KQV>
__global__ __launch_bounds__(THREADS) void k_up(
    const float* __restrict__ x,        // for recompute fallback
    const float* __restrict__ w_down,   // for recompute fallback
    const float* __restrict__ ws_kqv,
    const float* __restrict__ ws_gram,
    const float* __restrict__ w_up,     // [48, 8]
    float* __restrict__ out)            // [B, 48, 4096]
{
    const int blk = blockIdx.x;
    const int b = blk / SPLIT;
    const int s = blk % SPLIT;
    const int t = threadIdx.x;

    __shared__ float s_wu[CIN * CBOT];
    __shared__ float s_wdT[CIN * CBOT];
    __shared__ float s_g[36];
    __shared__ float s_am[CBOT * CBOT];

    for (int i = t; i < CIN * CBOT; i += THREADS) {
        s_wu[i] = w_up[i];
        if (!LOAD_KQV) {
            const int c = i >> 3, o = i & 7;
            s_wdT[i] = w_down[o * CIN + c];
        }
    }
    // full gram for this batch: sum the SPLIT partials
    if (t < 36) {
        float v = 0.0f;
        #pragma unroll
        for (int ss = 0; ss < SPLIT; ++ss)
            v += ws_gram[(size_t)(b * SPLIT + ss) * 36 + t];
        s_g[t] = v;
    }
    __syncthreads();

    if (t < 8) {
        float row[8];
        #pragma unroll
        for (int j = 0; j < 8; ++j) {
            const int i2 = t < j ? t : j;
            const int j2 = t < j ? j : t;
            const int tri = i2 * 8 - (i2 * (i2 - 1)) / 2 + (j2 - i2);
            row[j] = s_g[tri] * SCALE_;
        }
        float m = row[0];
        #pragma unroll
        for (int j = 1; j < 8; ++j) m = fmaxf(m, row[j]);
        float sum = 0.0f;
        #pragma unroll
        for (int j = 0; j < 8; ++j) { row[j] = __expf(row[j] - m); sum += row[j]; }
        const float inv = 1.0f / sum;
        #pragma unroll
        for (int j = 0; j < 8; ++j) s_am[t * 8 + j] = row[j] * inv;
    }
    __syncthreads();

    const int h0 = s * CHUNK + (t << 2);

    float kqv[CBOT][4];
    if (LOAD_KQV) {
        const float* kb = ws_kqv + (size_t)b * (CBOT * H_);
        #pragma unroll
        for (int o = 0; o < CBOT; ++o) {
            const float4 v = *reinterpret_cast<const float4*>(kb + o * H_ + h0);
            kqv[o][0] = v.x; kqv[o][1] = v.y; kqv[o][2] = v.z; kqv[o][3] = v.w;
        }
    } else {
        const float* xb = x + (size_t)b * (CIN * H_);
        #pragma unroll
        for (int o = 0; o < CBOT; ++o)
            kqv[o][0] = kqv[o][1] = kqv[o][2] = kqv[o][3] = 0.0f;
        #pragma unroll 8
        for (int c = 0; c < CIN; ++c) {
            const float4 xv = *reinterpret_cast<const float4*>(xb + c * H_ + h0);
            #pragma unroll
            for (int o = 0; o < CBOT; ++o) {
                const float w = s_wdT[c * CBOT + o];
                kqv[o][0] += w * xv.x;
                kqv[o][1] += w * xv.y;
                kqv[o][2] += w * xv.z;
                kqv[o][3] += w * xv.w;
            }
        }
    }

    float z[CBOT][4];
    #pragma unroll
    for (int o = 0; o < CBOT; ++o) {
        float a0 = 0.f, a1 = 0.f, a2 = 0.f, a3 = 0.f;
        #pragma unroll
        for (int j = 0; j < CBOT; ++j) {
            const float a = s_am[o * 8 + j];
            a0 += a * kqv[j][0];
            a1 += a * kqv[j][1];
            a2 += a * kqv[j][2];
            a3 += a * kqv[j][3];
        }
        z[o][0] = a0; z[o][1] = a1; z[o][2] = a2; z[o][3] = a3;
    }

    float* ob = out + (size_t)b * (CIN * H_);
    #pragma unroll 8
    for (int c = 0; c < CIN; ++c) {
        float4 r;
        r.x = r.y = r.z = r.w = 0.0f;
        #pragma unroll
        for (int o = 0; o < CBOT; ++o) {
            const float w = s_wu[c * CBOT + o];
            r.x += w * z[o][0];
            r.y += w * z[o][1];
            r.z += w * z[o][2];
            r.w += w * z[o][3];
        }
        *reinterpret_cast<float4*>(ob + c * H_ + h0) = r;
    }
}

extern "C" void kernel_launch(void* const* d_in, const int* in_sizes, int n_in,
                              void* d_out, int out_size, void* d_ws, size_t ws_size,
                              hipStream_t stream) {
    const float* x      = (const float*)d_in[0];
    const float* w_down = (const float*)d_in[1];
    const float* w_up   = (const float*)d_in[2];
    float* out          = (float*)d_out;

    const size_t kqv_elems  = (size_t)B_ * CBOT * H_;              // 8.39M floats
    const size_t gram_elems = (size_t)B_ * SPLIT * 36;
    const size_t need_bytes = (kqv_elems + gram_elems) * sizeof(float);

    const dim3 grid(B_ * SPLIT);
    const dim3 block(THREADS);

    if (ws_size >= need_bytes) {
        float* ws_kqv  = (float*)d_ws;
        float* ws_gram = ws_kqv + kqv_elems;
        hipLaunchKernelGGL((k_down<true>),  grid, block, 0, stream,
                           x, w_down, ws_kqv, ws_gram);
        hipLaunchKernelGGL((k_up<true>),    grid, block, 0, stream,
                           x, w_down, ws_kqv, ws_gram, w_up, out);
    } else {
        // gram partials only (needs ~295 KB)
        float* ws_gram = (float*)d_ws;
        hipLaunchKernelGGL((k_down<false>), grid, block, 0, stream,
                           x, w_down, nullptr, ws_gram);
        hipLaunchKernelGGL((k_up<false>),   grid, block, 0, stream,
                           x, w_down, nullptr, ws_gram, w_up, out);
    }
}